// Round 21
// baseline (435.904 us; speedup 1.0000x reference)
//
#include <hip/hip_runtime.h>
#include <hip/hip_bf16.h>

// Problem constants: B=8, S=512, H=768, NH=4, DH=192, N=4096, W<=8
#define Bb 8
#define Ss 512
#define Hh 768
#define NHh 4
#define Nn 4096
#define ROWS (Bb * Nn)      // 32768
#define SCB 128             // scan blocks (ROWS/256)
#define CHROWS 16384        // ffn1 chunk rows (2 launches cover worst case)

typedef _Float16 f16x8 __attribute__((ext_vector_type(8)));
typedef _Float16 f16x4 __attribute__((ext_vector_type(4)));
typedef _Float16 f16x2 __attribute__((ext_vector_type(2)));
typedef float f32x4 __attribute__((ext_vector_type(4)));

#define DEVINL __device__ __forceinline__

DEVINL void gld_lds16(const void* g, void* l) {
  __builtin_amdgcn_global_load_lds(
      (const __attribute__((address_space(1))) void*)g,
      (__attribute__((address_space(3))) void*)l, 16, 0, 0);
}

template <int V>
DEVINL void wait_vmcnt() {
  if constexpr (V == 0) asm volatile("s_waitcnt vmcnt(0)" ::: "memory");
  else if constexpr (V == 3) asm volatile("s_waitcnt vmcnt(3)" ::: "memory");
  else if constexpr (V == 4) asm volatile("s_waitcnt vmcnt(4)" ::: "memory");
  else if constexpr (V == 6) asm volatile("s_waitcnt vmcnt(6)" ::: "memory");
  else if constexpr (V == 8) asm volatile("s_waitcnt vmcnt(8)" ::: "memory");
}

DEVINL float block_sum256(float v, float* red) {
#pragma unroll
  for (int o = 32; o; o >>= 1) v += __shfl_xor(v, o, 64);
  const int wid = threadIdx.x >> 6, lane = threadIdx.x & 63;
  if (lane == 0) red[wid] = v;
  __syncthreads();
  float r = red[0] + red[1] + red[2] + red[3];
  __syncthreads();
  return r;
}

// ---------------- PE table: pet[s*384+t] = (sin, cos)(s * div(t)) -----------
__global__ __launch_bounds__(256) void pet_kernel(float2* __restrict__ pet) {
  int i = blockIdx.x * 256 + threadIdx.x;  // 0 .. 512*384
  int t = i % 384;
  int s = i / 384;
  float div = expf(-(float)t * 0.02398526138535465f);  // ln(10000)/384
  float ang = (float)s * div;
  float2 o;
  o.x = sinf(ang);
  o.y = cosf(ang);
  pet[i] = o;
}

// ---------------- x = token_reps + pe (table) (fp32 -> fp16) ----------------
__global__ __launch_bounds__(256) void x_kernel(const float* __restrict__ tok,
                                                const float2* __restrict__ pet,
                                                _Float16* __restrict__ x) {
  int idx = blockIdx.x * 256 + threadIdx.x;  // pair index over B*S*384
  int t = idx % 384;
  int bs = idx / 384;
  int s = bs & (Ss - 1);
  const float2 pe = pet[s * 384 + t];
  const float2 tv = ((const float2*)tok)[(size_t)bs * 384 + t];
  f16x2 o;
  o[0] = (_Float16)(tv.x + pe.x);
  o[1] = (_Float16)(tv.y + pe.y);
  *(f16x2*)&x[(size_t)bs * Hh + 2 * t] = o;
}

// ---------------- q[o] = dq . Wq[o,:] + bq[o]  (768 blocks) -----------------
__global__ __launch_bounds__(256) void q_kernel(const float* __restrict__ dq,
                                                const float* __restrict__ ipw,
                                                const float* __restrict__ ipb,
                                                float* __restrict__ qout) {
  __shared__ float red[4];
  int o = blockIdx.x;
  const float* wr = ipw + (size_t)o * Hh;
  float s = 0.f;
#pragma unroll
  for (int e = 0; e < 3; e++) {
    int j = threadIdx.x + 256 * e;
    s += dq[j] * wr[j];
  }
  s = block_sum256(s, red);
  if (threadIdx.x == 0) qout[o] = s + ipb[o];
}

// ------ c[h*768+j] = sum_d q[h,d]*Wk[h*192+d, j]  (coalesced over j) --------
__global__ __launch_bounds__(256) void ck2_kernel(const float* __restrict__ q,
                                                  const float* __restrict__ ipw,
                                                  float* __restrict__ cout) {
  int bid = blockIdx.x;       // 12 blocks: h = bid/3, j-tile = bid%3
  int h = bid / 3;
  int j = (bid % 3) * 256 + threadIdx.x;
  const float* qp = q + h * 192;
  const float* wp = ipw + (size_t)(Hh + h * 192) * Hh + j;
  float acc = 0.f;
#pragma unroll 4
  for (int d = 0; d < 192; d++) acc += qp[d] * wp[(size_t)d * Hh];
  cout[h * Hh + j] = acc;
}

// ------------- sbias[h] = q_h . bk_h  (4 blocks) ----------------------------
__global__ __launch_bounds__(256) void sb_kernel(const float* __restrict__ q,
                                                 const float* __restrict__ ipb,
                                                 float* __restrict__ sbias) {
  __shared__ float red[4];
  int h = blockIdx.x;
  int t = threadIdx.x;
  float s = 0.f;
  if (t < 192) s = q[h * 192 + t] * ipb[Hh + h * 192 + t];
  s = block_sum256(s, red);
  if (t == 0) sbias[h] = s;
}

// --------- scores[b,h,s] = (c_h . x[b,s] + sbias[h]) / sqrt(192) ------------
__global__ __launch_bounds__(256) void score_kernel(
    const _Float16* __restrict__ x, const float* __restrict__ c,
    const float* __restrict__ sbias, float* __restrict__ scores) {
  int bs = blockIdx.x;  // b*S + s
  int wid = threadIdx.x >> 6, lane = threadIdx.x & 63;
  const _Float16* xr = x + (size_t)bs * Hh;
  const float* ch = c + wid * Hh;
  float s = 0.f;
#pragma unroll
  for (int e = 0; e < 12; e++) {
    int j = e * 64 + lane;
    s += (float)xr[j] * ch[j];
  }
#pragma unroll
  for (int o = 32; o; o >>= 1) s += __shfl_xor(s, o, 64);
  if (lane == 0) {
    int b = bs >> 9, pos = bs & (Ss - 1);
    scores[((size_t)(b * NHh + wid)) * Ss + pos] =
        (s + sbias[wid]) * 0.07216878364870322f;  // 1/sqrt(192)
  }
}

// ------------- fp32 -> fp16 elementwise convert (float4 per thread) ---------
__global__ __launch_bounds__(256) void cvt_kernel(const float* __restrict__ in,
                                                  _Float16* __restrict__ out) {
  int i = blockIdx.x * 256 + threadIdx.x;
  float4 f = ((const float4*)in)[i];
  f16x4 o;
  o[0] = (_Float16)f.x;
  o[1] = (_Float16)f.y;
  o[2] = (_Float16)f.z;
  o[3] = (_Float16)f.w;
  ((f16x4*)out)[i] = o;
}

// ------------- transpose + convert: in fp32 [R][C] -> out fp16 [C][R] -------
__global__ __launch_bounds__(256) void trcvt_kernel(const float* __restrict__ in,
                                                    _Float16* __restrict__ out,
                                                    int R, int C) {
  __shared__ float tile[32][33];
  int c0 = blockIdx.x * 32, r0 = blockIdx.y * 32;
  int tx = threadIdx.x & 31, ty0 = threadIdx.x >> 5;
#pragma unroll
  for (int ty = ty0; ty < 32; ty += 8)
    tile[ty][tx] = in[(size_t)(r0 + ty) * C + c0 + tx];
  __syncthreads();
#pragma unroll
  for (int ty = ty0; ty < 32; ty += 8)
    out[(size_t)(c0 + ty) * R + r0 + tx] = (_Float16)tile[tx][ty];
}

// ---------------- deterministic compaction scan (no atomics) ----------------
__global__ __launch_bounds__(256) void scan1_kernel(const int* __restrict__ mask,
                                                    int* __restrict__ bsum) {
  int r = blockIdx.x * 256 + threadIdx.x;
  unsigned long long b = __ballot(mask[r] != 0);
  __shared__ int wsum[4];
  int lane = threadIdx.x & 63, wid = threadIdx.x >> 6;
  if (lane == 0) wsum[wid] = __popcll(b);
  __syncthreads();
  if (threadIdx.x == 0)
    bsum[blockIdx.x] = wsum[0] + wsum[1] + wsum[2] + wsum[3];
}
__global__ __launch_bounds__(64) void scan2_kernel(const int* __restrict__ bsum,
                                                   int* __restrict__ boff,
                                                   int* __restrict__ cnt) {
  if (threadIdx.x == 0) {
    int acc = 0;
    for (int i = 0; i < SCB; i++) {
      boff[i] = acc;
      acc += bsum[i];
    }
    *cnt = acc;
  }
}
__global__ __launch_bounds__(256) void cidx_kernel(const int* __restrict__ mask,
                                                   const int* __restrict__ boff,
                                                   int* __restrict__ cidx) {
  int r = blockIdx.x * 256 + threadIdx.x;
  int m = mask[r] != 0;
  unsigned long long b = __ballot(m);
  __shared__ int wsum[4];
  int lane = threadIdx.x & 63, wid = threadIdx.x >> 6;
  if (lane == 0) wsum[wid] = __popcll(b);
  __syncthreads();
  int pre = 0;
#pragma unroll
  for (int i = 0; i < 3; i++)
    if (i < wid) pre += wsum[i];
  pre += __popcll(b & ((1ULL << lane) - 1));
  if (m) cidx[r] = boff[blockIdx.x] + pre;
}

// ---- r13/r15-proven two-barrier 3-buffer pipelined iteration ---------------
#define ITER_RESTAGE(b, knext)              \
  do {                                      \
    wait_vmcnt<2 * LPS>();                  \
    __builtin_amdgcn_s_barrier();           \
    COMPUTE(b);                             \
    __builtin_amdgcn_s_barrier();           \
    STAGE(b, (knext));                      \
  } while (0)
#define PIPE_MAIN()                         \
  const int nt = K >> 5;                    \
  STAGE(0, 0);                              \
  STAGE(1, 32);                             \
  STAGE(2, 64);                             \
  int t = 0;                                \
  for (; t <= nt - 6; t += 3) {             \
    ITER_RESTAGE(0, (t + 3) * 32);          \
    ITER_RESTAGE(1, (t + 4) * 32);          \
    ITER_RESTAGE(2, (t + 5) * 32);          \
  }                                         \
  wait_vmcnt<2 * LPS>();                    \
  __builtin_amdgcn_s_barrier();             \
  COMPUTE(0);                               \
  wait_vmcnt<LPS>();                        \
  __builtin_amdgcn_s_barrier();             \
  COMPUTE(1);                               \
  wait_vmcnt<0>();                          \
  __builtin_amdgcn_s_barrier();             \
  COMPUTE(2);

// ---------------- 8-wave NT GEMM (256x128), wave 64x64 — r15-proven ---------
// mbase: global compact-row offset of this launch's chunk (gate only;
// A/C pointers pre-offset by host). Grid sized to the chunk -> empty-tail
// dispatch tax avoided (r19/r20 evidence: ffn1 113 -> 102 us per dispatch).
template <int RELU>
__global__ __launch_bounds__(512, 4) void gemm8_nt(
    const _Float16* __restrict__ A, const _Float16* __restrict__ W,
    const float* __restrict__ bias, _Float16* __restrict__ C, int N, int K,
    int nn, int mbase, const int* __restrict__ mcount) {
  const int bid = (int)blockIdx.x;
  const int mi = (bid >> 3) / nn;
  const int nt_ = (bid >> 3) - mi * nn;
  const long m0 = (long)(mi * 8 + (bid & 7)) * 256;
  const long n0 = (long)nt_ * 128;
  if (mcount && (long)mbase + m0 >= (long)*mcount) return;
  __shared__ __align__(16) _Float16 As[3][256 * 32];   // 48KB
  __shared__ __align__(16) _Float16 Bs[3][128 * 32];   // 24KB
  const int tid = threadIdx.x;
  const int w = tid >> 6;     // 0..7
  const int lane = tid & 63;
  constexpr int LPS = 3;

  const int rA0 = w * 16 + (lane >> 2);
  const int rA1 = rA0 + 128;
  const int cb = lane & 3;
  const int swA0 = (cb ^ ((rA0 >> 1) & 3)) * 8;
  const int swA1 = (cb ^ ((rA1 >> 1) & 3)) * 8;
  const _Float16* gA0 = A + (m0 + rA0) * K + swA0;
  const _Float16* gA1 = A + (m0 + rA1) * K + swA1;
  const _Float16* gB0 = W + (n0 + rA0) * K + swA0;

  const int wr = (w >> 1) * 64;
  const int wc = (w & 1) * 64;
  const int fr = lane & 15;
  const int fkb = lane >> 4;

  f32x4 acc[4][4];
#pragma unroll
  for (int mi2 = 0; mi2 < 4; mi2++)
#pragma unroll
    for (int ni = 0; ni < 4; ni++) acc[mi2][ni] = (f32x4){0.f, 0.f, 0.f, 0.f};

#define STAGE(buf, k0)                                   \
  do {                                                   \
    gld_lds16(gA0 + (k0), &As[buf][w * 512]);            \
    gld_lds16(gA1 + (k0), &As[buf][(w + 8) * 512]);      \
    gld_lds16(gB0 + (k0), &Bs[buf][w * 512]);            \
  } while (0)

#define COMPUTE(buf)                                                          \
  do {                                                                        \
    f16x8 af[4], bf[4];                                                       \
    _Pragma("unroll") for (int i = 0; i < 4; i++) {                           \
      int r_ = wr + i * 16 + fr;                                              \
      af[i] = *(const f16x8*)&As[buf][r_ * 32 + ((fkb ^ ((r_ >> 1) & 3)) * 8)]; \
    }                                                                         \
    _Pragma("unroll") for (int i = 0; i < 4; i++) {                           \
      int r_ = wc + i * 16 + fr;                                              \
      bf[i] = *(const f16x8*)&Bs[buf][r_ * 32 + ((fkb ^ ((r_ >> 1) & 3)) * 8)]; \
    }                                                                         \
    __builtin_amdgcn_s_setprio(1);                                            \
    _Pragma("unroll") for (int mi2 = 0; mi2 < 4; mi2++)                       \
        _Pragma("unroll") for (int ni = 0; ni < 4; ni++)                      \
            acc[mi2][ni] = __builtin_amdgcn_mfma_f32_16x16x32_f16(            \
                af[mi2], bf[ni], acc[mi2][ni], 0, 0, 0);                      \
    __builtin_amdgcn_s_setprio(0);                                            \
  } while (0)

  PIPE_MAIN()
#undef STAGE
#undef COMPUTE

  // epilogue: C/D layout col=lane&15, row=(lane>>4)*4+i  (m89-verified)
  const int crow = (lane >> 4) * 4;
  const int ccol = lane & 15;
  float bv[4];
#pragma unroll
  for (int ni = 0; ni < 4; ni++)
    bv[ni] = bias ? bias[n0 + wc + ni * 16 + ccol] : 0.f;
#pragma unroll
  for (int mi2 = 0; mi2 < 4; mi2++)
#pragma unroll
    for (int ni = 0; ni < 4; ni++)
#pragma unroll
      for (int i = 0; i < 4; i++) {
        float v = acc[mi2][ni][i] + bv[ni];
        if (RELU) v = fmaxf(v, 0.f);
        C[(m0 + wr + mi2 * 16 + crow + i) * (long)N + (n0 + wc + ni * 16 + ccol)] =
            (_Float16)v;
      }
}

// ------- span pooling into precomputed compact slots (no atomics) -----------
__global__ __launch_bounds__(192) void pool_kernel(
    const _Float16* __restrict__ v, const float* __restrict__ scores,
    const int* __restrict__ span_ids, const int* __restrict__ span_masks,
    _Float16* __restrict__ attn, const int* __restrict__ cidx) {
  int r = blockIdx.x;  // b*N + n
  if (span_masks[r] == 0) return;
  int slot = cidx[r];
  int i = threadIdx.x;   // 0..191
  int h = i / 48;        // head
  int d0 = i * 4;
  int b = r >> 12;
  int st = span_ids[2 * r], en = span_ids[2 * r + 1];
  int wdt = en - st;  // 1..8 (block-uniform)
  const float* sc = scores + ((size_t)(b * NHh + h)) * Ss + st;
  float w[8];
  float mx = -1e30f;
#pragma unroll
  for (int j = 0; j < 8; j++) {
    float t = (j < wdt) ? sc[j] : -1e30f;
    w[j] = t;
    mx = fmaxf(mx, t);
  }
  float sum = 0.f;
#pragma unroll
  for (int j = 0; j < 8; j++) {
    float e = (j < wdt) ? expf(w[j] - mx) : 0.f;
    w[j] = e;
    sum += e;
  }
  float inv = 1.f / sum;
  float a0 = 0.f, a1 = 0.f, a2 = 0.f, a3 = 0.f;
#pragma unroll
  for (int j = 0; j < 8; j++) {
    if (j < wdt) {  // block-uniform branch
      f16x4 vv = *(const f16x4*)(v + ((size_t)(b * Ss + st + j)) * Hh + d0);
      float wj = w[j] * inv;
      a0 += wj * (float)vv[0];
      a1 += wj * (float)vv[1];
      a2 += wj * (float)vv[2];
      a3 += wj * (float)vv[3];
    }
  }
  f16x4 o;
  o[0] = (_Float16)a0;
  o[1] = (_Float16)a1;
  o[2] = (_Float16)a2;
  o[3] = (_Float16)a3;
  *(f16x4*)&attn[(size_t)slot * Hh + d0] = o;
}

// ------------- LN0: h1 = LN(X + dq) in-place over compact rows --------------
__global__ __launch_bounds__(256) void ln0_kernel(
    _Float16* __restrict__ X, const float* __restrict__ AddV,
    const float* __restrict__ g, const float* __restrict__ bta,
    const int* __restrict__ mcount) {
  __shared__ float red[4];
  int r = blockIdx.x;
  if (r >= *mcount) return;
  int t = threadIdx.x;
  float xv[3];
#pragma unroll
  for (int e = 0; e < 3; e++) {
    int d = t + 256 * e;
    xv[e] = (float)X[(size_t)r * Hh + d] + AddV[d];
  }
  float s = xv[0] + xv[1] + xv[2];
  s = block_sum256(s, red);
  float mean = s * (1.f / 768.f);
  float vs = 0.f;
#pragma unroll
  for (int e = 0; e < 3; e++) {
    float d = xv[e] - mean;
    vs += d * d;
  }
  vs = block_sum256(vs, red);
  float inv = rsqrtf(vs * (1.f / 768.f) + 1e-5f);
#pragma unroll
  for (int e = 0; e < 3; e++) {
    int d = t + 256 * e;
    X[(size_t)r * Hh + d] = (_Float16)((xv[e] - mean) * inv * g[d] + bta[d]);
  }
}

// ------------- LN1: scatter out[r] = LN(F2[c]+h1[c]) or zeros ---------------
__global__ __launch_bounds__(256) void ln1_kernel(
    const _Float16* __restrict__ F2c, const _Float16* __restrict__ h1c,
    const int* __restrict__ cidx, const float* __restrict__ g,
    const float* __restrict__ bta, const int* __restrict__ mask,
    float* __restrict__ out) {
  __shared__ float red[4];
  int r = blockIdx.x;
  int t = threadIdx.x;
  float* orow = out + (size_t)r * Hh;
  if (mask[r] == 0) {  // block-uniform
#pragma unroll
    for (int e = 0; e < 3; e++) orow[t + 256 * e] = 0.f;
    return;
  }
  int c = cidx[r];
  float xv[3];
#pragma unroll
  for (int e = 0; e < 3; e++) {
    int d = t + 256 * e;
    xv[e] = (float)F2c[(size_t)c * Hh + d] + (float)h1c[(size_t)c * Hh + d];
  }
  float s = xv[0] + xv[1] + xv[2];
  s = block_sum256(s, red);
  float mean = s * (1.f / 768.f);
  float vs = 0.f;
#pragma unroll
  for (int e = 0; e < 3; e++) {
    float d = xv[e] - mean;
    vs += d * d;
  }
  vs = block_sum256(vs, red);
  float inv = rsqrtf(vs * (1.f / 768.f) + 1e-5f);
#pragma unroll
  for (int e = 0; e < 3; e++) {
    int d = t + 256 * e;
    orow[d] = (xv[e] - mean) * inv * g[d] + bta[d];
  }
}

// ===========================================================================
extern "C" void kernel_launch(void* const* d_in, const int* in_sizes, int n_in,
                              void* d_out, int out_size, void* d_ws,
                              size_t ws_size, hipStream_t stream) {
  (void)out_size;
  // --- input sanity guard: mismatch -> zero-ish output signature ------------
  if (n_in != 14) return;
  if (in_sizes[0] != 3145728 || in_sizes[2] != 1769472 ||
      in_sizes[3] != 2304 || in_sizes[4] != 589824 ||
      in_sizes[8] != 2359296 || in_sizes[9] != 3072 ||
      in_sizes[12] != 65536 || in_sizes[13] != 32768)
    return;

  const float* tok   = (const float*)d_in[0];
  const float* dq    = (const float*)d_in[1];
  const float* ipw   = (const float*)d_in[2];   // [2304][768]
  const float* ipb   = (const float*)d_in[3];   // [2304]
  const float* outw  = (const float*)d_in[4];   // [768][768]
  const float* outb  = (const float*)d_in[5];
  const float* lng   = (const float*)d_in[6];
  const float* lnb   = (const float*)d_in[7];
  const float* w1    = (const float*)d_in[8];   // [768][3072]
  const float* b1    = (const float*)d_in[9];
  const float* w2    = (const float*)d_in[10];  // [3072][768]
  const float* b2    = (const float*)d_in[11];
  const int* spid    = (const int*)d_in[12];
  const int* spmask  = (const int*)d_in[13];

  char* ws = (char*)d_ws;
  size_t off = 0;
  auto alloc = [&](size_t bytes) {
    size_t r = off;
    off = (off + bytes + 255) & ~(size_t)255;
    return r;
  };
  _Float16* X16  = (_Float16*)(ws + alloc((size_t)Bb * Ss * Hh * 2));     // 6.3MB
  float* SC      = (float*)(ws + alloc((size_t)Bb * NHh * Ss * 4));       // 64KB
  float* Q       = (float*)(ws + alloc(768 * 4));
  float* Cc      = (float*)(ws + alloc(3072 * 4));
  float* SB      = (float*)(ws + alloc(4 * 4));
  _Float16* WV16 = (_Float16*)(ws + alloc((size_t)768 * 768 * 2));        // 1.2MB
  _Float16* OW16 = (_Float16*)(ws + alloc((size_t)768 * 768 * 2));        // 1.2MB
  _Float16* WT1  = (_Float16*)(ws + alloc((size_t)3072 * 768 * 2));       // 4.7MB
  _Float16* WT2  = (_Float16*)(ws + alloc((size_t)768 * 3072 * 2));       // 4.7MB
  // compact-row buffers, worst-case ROWS active:
  _Float16* ATTN = (_Float16*)(ws + alloc((size_t)ROWS * Hh * 2));        // 50.3MB (later reused as F2)
  _Float16* PROJ = (_Float16*)(ws + alloc((size_t)ROWS * Hh * 2));        // 50.3MB (h1 after LN0)
  _Float16* F1   = (_Float16*)(ws + alloc((size_t)ROWS * 3072 * 2));      // 201.3MB
  if (ws_size < off) return;  // total 320,158,976 B <= bound proven in r8
  _Float16* F2 = ATTN;  // ATTN dead after proj GEMM

  // Compaction metadata aliases the X16 region (X16 dead after V GEMM).
  int* CIDX = (int*)X16;                    // 32768 ints = 128KB
  int* BSUM = (int*)X16 + ROWS;             // 128 ints
  int* BOFF = (int*)X16 + ROWS + SCB;       // 128 ints
  int* CNT  = (int*)X16 + ROWS + 2 * SCB;   // 1 int

  // d_out staging (100.66MB, fully overwritten by ln1 at the end):
  // V16 at [0, 6.3MB); PE table at [8MB, 9.6MB).
  _Float16* V16 = (_Float16*)d_out;
  float2* PET = (float2*)((char*)d_out + 8388608);

  // weight prep
  cvt_kernel<<<576, 256, 0, stream>>>(ipw + (size_t)1536 * 768, WV16);  // Wv
  cvt_kernel<<<576, 256, 0, stream>>>(outw, OW16);
  trcvt_kernel<<<dim3(96, 24), 256, 0, stream>>>(w1, WT1, 768, 3072);
  trcvt_kernel<<<dim3(24, 96), 256, 0, stream>>>(w2, WT2, 3072, 768);

  // PE table (trig once per (s,t), not per batch) then x = tok + pe
  pet_kernel<<<(Ss * 384) / 256, 256, 0, stream>>>(PET);
  x_kernel<<<(Bb * Ss * 384) / 256, 256, 0, stream>>>(tok, PET, X16);
  // q, c (coalesced), sbias
  q_kernel<<<768, 256, 0, stream>>>(dq, ipw, ipb, Q);
  ck2_kernel<<<12, 256, 0, stream>>>(Q, ipw, Cc);
  sb_kernel<<<4, 256, 0, stream>>>(Q, ipb, SB);
  // scores
  score_kernel<<<Bb * Ss, 256, 0, stream>>>(X16, Cc, SB, SC);
  // V = x @ Wv^T + bv -> V16 (in d_out)  [gemm8: 16m x 6n x 8 = 768 blocks]
  gemm8_nt<0><<<768, 512, 0, stream>>>(X16, WV16, ipb + 1536, V16,
                                       768, 768, 6, 0, nullptr);
  // deterministic compaction scan (X16 now dead; aliased region)
  scan1_kernel<<<SCB, 256, 0, stream>>>(spmask, BSUM);
  scan2_kernel<<<1, 64, 0, stream>>>(BSUM, BOFF, CNT);
  cidx_kernel<<<SCB, 256, 0, stream>>>(spmask, BOFF, CIDX);
  // span pooling -> compact ATTN via CIDX (vectorized f16x4, 192 thr)
  pool_kernel<<<ROWS, 192, 0, stream>>>(V16, SC, spid, spmask, ATTN, CIDX);
  // proj = ATTN @ out_w^T + out_b -> PROJ  [8-wave 256x128: 128m x 6n]
  gemm8_nt<0><<<768, 512, 0, stream>>>(ATTN, OW16, outb, PROJ,
                                       768, 768, 6, 0, CNT);
  // h1 = LN(proj + dq) in-place (compact rows; gated)
  ln0_kernel<<<ROWS, 256, 0, stream>>>(PROJ, dq, lng, lnb, CNT);
  // ffn1 = relu(h1 @ w1 + b1) — two chunk launches, grid matched to the
  // typical active count (chunk 1 fully gated when active <= 16384)
  for (int ch = 0; ch < 2; ch++) {
    const int mb = ch * CHROWS;
    gemm8_nt<1><<<1536, 512, 0, stream>>>(
        PROJ + (size_t)mb * Hh, WT1, b1, F1 + (size_t)mb * 3072,
        3072, 768, 24, mb, CNT);
  }
  // ffn2 = ffn1 @ w2 + b2 -> F2  [8-wave 256x128: 128m x 6n = 768 blocks]
  gemm8_nt<0><<<768, 512, 0, stream>>>(F1, WT2, b2, F2,
                                       768, 3072, 6, 0, CNT);
  // out[r] = LN(F2[cidx[r]] + h1[cidx[r]]) or zeros -> fp32 d_out
  ln1_kernel<<<ROWS, 256, 0, stream>>>(F2, PROJ, CIDX, lng, lnb, spmask,
                                       (float*)d_out);
}

// Round 22
// 364.608 us; speedup vs baseline: 1.1955x; 1.1955x over previous
//
#include <hip/hip_runtime.h>
#include <hip/hip_bf16.h>

// Problem constants: B=8, S=512, H=768, NH=4, DH=192, N=4096, W<=8
#define Bb 8
#define Ss 512
#define Hh 768
#define NHh 4
#define Nn 4096
#define ROWS (Bb * Nn)      // 32768
#define SCB 128             // scan blocks (ROWS/256)

typedef _Float16 f16x8 __attribute__((ext_vector_type(8)));
typedef _Float16 f16x4 __attribute__((ext_vector_type(4)));
typedef _Float16 f16x2 __attribute__((ext_vector_type(2)));
typedef float f32x4 __attribute__((ext_vector_type(4)));

#define DEVINL __device__ __forceinline__

DEVINL void gld_lds16(const void* g, void* l) {
  __builtin_amdgcn_global_load_lds(
      (const __attribute__((address_space(1))) void*)g,
      (__attribute__((address_space(3))) void*)l, 16, 0, 0);
}

template <int V>
DEVINL void wait_vmcnt() {
  if constexpr (V == 0) asm volatile("s_waitcnt vmcnt(0)" ::: "memory");
  else if constexpr (V == 3) asm volatile("s_waitcnt vmcnt(3)" ::: "memory");
  else if constexpr (V == 4) asm volatile("s_waitcnt vmcnt(4)" ::: "memory");
  else if constexpr (V == 6) asm volatile("s_waitcnt vmcnt(6)" ::: "memory");
  else if constexpr (V == 8) asm volatile("s_waitcnt vmcnt(8)" ::: "memory");
}

DEVINL float block_sum256(float v, float* red) {
#pragma unroll
  for (int o = 32; o; o >>= 1) v += __shfl_xor(v, o, 64);
  const int wid = threadIdx.x >> 6, lane = threadIdx.x & 63;
  if (lane == 0) red[wid] = v;
  __syncthreads();
  float r = red[0] + red[1] + red[2] + red[3];
  __syncthreads();
  return r;
}

// ---------------- x = token_reps + pos_encoding (fp32 in -> fp16 out) -------
__global__ __launch_bounds__(256) void x_kernel(const float* __restrict__ tok,
                                                _Float16* __restrict__ x) {
  int idx = blockIdx.x * 256 + threadIdx.x;  // pair index over B*S*384
  int t = idx % 384;
  int bs = idx / 384;
  int s = bs & (Ss - 1);
  float div = expf(-(float)t * 0.02398526138535465f);  // ln(10000)/384
  float ang = (float)s * div;
  float sv = sinf(ang), cv = cosf(ang);
  const float2 tv = ((const float2*)tok)[(size_t)bs * 384 + t];
  f16x2 o;
  o[0] = (_Float16)(tv.x + sv);
  o[1] = (_Float16)(tv.y + cv);
  *(f16x2*)&x[(size_t)bs * Hh + 2 * t] = o;
}

// ---------------- q[o] = dq . Wq[o,:] + bq[o]  (768 blocks) -----------------
__global__ __launch_bounds__(256) void q_kernel(const float* __restrict__ dq,
                                                const float* __restrict__ ipw,
                                                const float* __restrict__ ipb,
                                                float* __restrict__ qout) {
  __shared__ float red[4];
  int o = blockIdx.x;
  const float* wr = ipw + (size_t)o * Hh;
  float s = 0.f;
#pragma unroll
  for (int e = 0; e < 3; e++) {
    int j = threadIdx.x + 256 * e;
    s += dq[j] * wr[j];
  }
  s = block_sum256(s, red);
  if (threadIdx.x == 0) qout[o] = s + ipb[o];
}

// ------- c[h*768+j] = sum_d q[h,d]*Wk[h*192+d, j]; sbias[h]=q_h.bk_h --------
__global__ __launch_bounds__(256) void c_kernel(const float* __restrict__ q,
                                                const float* __restrict__ ipw,
                                                const float* __restrict__ ipb,
                                                float* __restrict__ cout,
                                                float* __restrict__ sbias) {
  __shared__ float red[4];
  int bid = blockIdx.x;
  int t = threadIdx.x;
  if (bid < 3072) {
    int h = bid / Hh;
    int j = bid - h * Hh;
    float s = 0.f;
    if (t < 192) s = q[h * 192 + t] * ipw[(size_t)(Hh + h * 192 + t) * Hh + j];
    s = block_sum256(s, red);
    if (t == 0) cout[bid] = s;
  } else {
    int h = bid - 3072;
    float s = 0.f;
    if (t < 192) s = q[h * 192 + t] * ipb[Hh + h * 192 + t];
    s = block_sum256(s, red);
    if (t == 0) sbias[h] = s;
  }
}

// --------- scores[b,h,s] = (c_h . x[b,s] + sbias[h]) / sqrt(192) ------------
__global__ __launch_bounds__(256) void score_kernel(
    const _Float16* __restrict__ x, const float* __restrict__ c,
    const float* __restrict__ sbias, float* __restrict__ scores) {
  int bs = blockIdx.x;  // b*S + s
  int wid = threadIdx.x >> 6, lane = threadIdx.x & 63;
  const _Float16* xr = x + (size_t)bs * Hh;
  const float* ch = c + wid * Hh;
  float s = 0.f;
#pragma unroll
  for (int e = 0; e < 12; e++) {
    int j = e * 64 + lane;
    s += (float)xr[j] * ch[j];
  }
#pragma unroll
  for (int o = 32; o; o >>= 1) s += __shfl_xor(s, o, 64);
  if (lane == 0) {
    int b = bs >> 9, pos = bs & (Ss - 1);
    scores[((size_t)(b * NHh + wid)) * Ss + pos] =
        (s + sbias[wid]) * 0.07216878364870322f;  // 1/sqrt(192)
  }
}

// ------------- fp32 -> fp16 elementwise convert (float4 per thread) ---------
__global__ __launch_bounds__(256) void cvt_kernel(const float* __restrict__ in,
                                                  _Float16* __restrict__ out) {
  int i = blockIdx.x * 256 + threadIdx.x;
  float4 f = ((const float4*)in)[i];
  f16x4 o;
  o[0] = (_Float16)f.x;
  o[1] = (_Float16)f.y;
  o[2] = (_Float16)f.z;
  o[3] = (_Float16)f.w;
  ((f16x4*)out)[i] = o;
}

// ------------- transpose + convert: in fp32 [R][C] -> out fp16 [C][R] -------
__global__ __launch_bounds__(256) void trcvt_kernel(const float* __restrict__ in,
                                                    _Float16* __restrict__ out,
                                                    int R, int C) {
  __shared__ float tile[32][33];
  int c0 = blockIdx.x * 32, r0 = blockIdx.y * 32;
  int tx = threadIdx.x & 31, ty0 = threadIdx.x >> 5;
#pragma unroll
  for (int ty = ty0; ty < 32; ty += 8)
    tile[ty][tx] = in[(size_t)(r0 + ty) * C + c0 + tx];
  __syncthreads();
#pragma unroll
  for (int ty = ty0; ty < 32; ty += 8)
    out[(size_t)(c0 + ty) * R + r0 + tx] = (_Float16)tile[tx][ty];
}

// ---------------- deterministic compaction scan (no atomics) ----------------
__global__ __launch_bounds__(256) void scan1_kernel(const int* __restrict__ mask,
                                                    int* __restrict__ bsum) {
  int r = blockIdx.x * 256 + threadIdx.x;
  unsigned long long b = __ballot(mask[r] != 0);
  __shared__ int wsum[4];
  int lane = threadIdx.x & 63, wid = threadIdx.x >> 6;
  if (lane == 0) wsum[wid] = __popcll(b);
  __syncthreads();
  if (threadIdx.x == 0)
    bsum[blockIdx.x] = wsum[0] + wsum[1] + wsum[2] + wsum[3];
}
__global__ __launch_bounds__(64) void scan2_kernel(const int* __restrict__ bsum,
                                                   int* __restrict__ boff,
                                                   int* __restrict__ cnt) {
  if (threadIdx.x == 0) {
    int acc = 0;
    for (int i = 0; i < SCB; i++) {
      boff[i] = acc;
      acc += bsum[i];
    }
    *cnt = acc;
  }
}
__global__ __launch_bounds__(256) void cidx_kernel(const int* __restrict__ mask,
                                                   const int* __restrict__ boff,
                                                   int* __restrict__ cidx) {
  int r = blockIdx.x * 256 + threadIdx.x;
  int m = mask[r] != 0;
  unsigned long long b = __ballot(m);
  __shared__ int wsum[4];
  int lane = threadIdx.x & 63, wid = threadIdx.x >> 6;
  if (lane == 0) wsum[wid] = __popcll(b);
  __syncthreads();
  int pre = 0;
#pragma unroll
  for (int i = 0; i < 3; i++)
    if (i < wid) pre += wsum[i];
  pre += __popcll(b & ((1ULL << lane) - 1));
  if (m) cidx[r] = boff[blockIdx.x] + pre;
}

// ---- r13/r15-proven two-barrier 3-buffer pipelined iteration ---------------
#define ITER_RESTAGE(b, knext)              \
  do {                                      \
    wait_vmcnt<2 * LPS>();                  \
    __builtin_amdgcn_s_barrier();           \
    COMPUTE(b);                             \
    __builtin_amdgcn_s_barrier();           \
    STAGE(b, (knext));                      \
  } while (0)
#define PIPE_MAIN()                         \
  const int nt = K >> 5;                    \
  STAGE(0, 0);                              \
  STAGE(1, 32);                             \
  STAGE(2, 64);                             \
  int t = 0;                                \
  for (; t <= nt - 6; t += 3) {             \
    ITER_RESTAGE(0, (t + 3) * 32);          \
    ITER_RESTAGE(1, (t + 4) * 32);          \
    ITER_RESTAGE(2, (t + 5) * 32);          \
  }                                         \
  wait_vmcnt<2 * LPS>();                    \
  __builtin_amdgcn_s_barrier();             \
  COMPUTE(0);                               \
  wait_vmcnt<LPS>();                        \
  __builtin_amdgcn_s_barrier();             \
  COMPUTE(1);                               \
  wait_vmcnt<0>();                          \
  __builtin_amdgcn_s_barrier();             \
  COMPUTE(2);

// ---------------- 4-wave NT GEMM (128x64) — used for V only -----------------
template <int RELU, int BN>
__global__ __launch_bounds__(256, 2) void gemm_nt(
    const _Float16* __restrict__ A, const _Float16* __restrict__ W,
    const float* __restrict__ bias, _Float16* __restrict__ C, int N, int K,
    int nn, const int* __restrict__ mcount) {
  const int bid = (int)blockIdx.x;
  const int mi = (bid >> 3) / nn;
  const int nt_ = (bid >> 3) - mi * nn;
  const long m0 = (long)(mi * 8 + (bid & 7)) * 128;
  const long n0 = (long)nt_ * BN;
  if (mcount && m0 >= (long)*mcount) return;
  __shared__ __align__(16) _Float16 As[3][128 * 32];
  __shared__ __align__(16) _Float16 Bs[3][BN * 32];
  const int tid = threadIdx.x;
  const int wid = tid >> 6;
  const int lane = tid & 63;
  constexpr int LPS = (BN == 128) ? 4 : 3;

  const int c0 = wid * 64 + lane;
  const int c1 = c0 + 256;
  const int sw0 = ((c0 & 3) ^ ((c0 >> 3) & 3)) * 8;
  const int sw1 = ((c1 & 3) ^ ((c1 >> 3) & 3)) * 8;
  const _Float16* gA0 = A + (m0 + (c0 >> 2)) * K + sw0;
  const _Float16* gA1 = A + (m0 + (c1 >> 2)) * K + sw1;
  const _Float16* gB0 = W + (n0 + (c0 >> 2)) * K + sw0;
  const _Float16* gB1 = W + (n0 + (c1 >> 2)) * K + sw1;

  const int wr = (wid >> 1) * 64;
  const int wc = (wid & 1) * (BN / 2);
  constexpr int NF = BN / 32;
  const int fr = lane & 15;
  const int fkb = lane >> 4;

  f32x4 acc[4][NF];
#pragma unroll
  for (int mi2 = 0; mi2 < 4; mi2++)
#pragma unroll
    for (int ni = 0; ni < NF; ni++) acc[mi2][ni] = (f32x4){0.f, 0.f, 0.f, 0.f};

#define STAGE(buf, k0)                                                  \
  do {                                                                  \
    gld_lds16(gA0 + (k0), &As[buf][wid * 512]);                         \
    gld_lds16(gA1 + (k0), &As[buf][2048 + wid * 512]);                  \
    gld_lds16(gB0 + (k0), &Bs[buf][wid * 512]);                         \
    if constexpr (BN == 128) gld_lds16(gB1 + (k0), &Bs[buf][2048 + wid * 512]); \
  } while (0)

#define COMPUTE(buf)                                                          \
  do {                                                                        \
    f16x8 af[4], bf[NF];                                                      \
    _Pragma("unroll") for (int i = 0; i < 4; i++) {                           \
      int r_ = wr + i * 16 + fr;                                              \
      af[i] = *(const f16x8*)&As[buf][r_ * 32 + ((fkb ^ ((r_ >> 1) & 3)) * 8)]; \
    }                                                                         \
    _Pragma("unroll") for (int i = 0; i < NF; i++) {                          \
      int r_ = wc + i * 16 + fr;                                              \
      bf[i] = *(const f16x8*)&Bs[buf][r_ * 32 + ((fkb ^ ((r_ >> 1) & 3)) * 8)]; \
    }                                                                         \
    __builtin_amdgcn_s_setprio(1);                                            \
    _Pragma("unroll") for (int mi2 = 0; mi2 < 4; mi2++)                       \
        _Pragma("unroll") for (int ni = 0; ni < NF; ni++)                     \
            acc[mi2][ni] = __builtin_amdgcn_mfma_f32_16x16x32_f16(            \
                af[mi2], bf[ni], acc[mi2][ni], 0, 0, 0);                      \
    __builtin_amdgcn_s_setprio(0);                                            \
  } while (0)

  PIPE_MAIN()
#undef STAGE
#undef COMPUTE

  const int crow = (lane >> 4) * 4;
  const int ccol = lane & 15;
  float bv[NF];
#pragma unroll
  for (int ni = 0; ni < NF; ni++)
    bv[ni] = bias ? bias[n0 + wc + ni * 16 + ccol] : 0.f;
#pragma unroll
  for (int mi2 = 0; mi2 < 4; mi2++)
#pragma unroll
    for (int ni = 0; ni < NF; ni++)
#pragma unroll
      for (int i = 0; i < 4; i++) {
        float v = acc[mi2][ni][i] + bv[ni];
        if (RELU) v = fmaxf(v, 0.f);
        C[(m0 + wr + mi2 * 16 + crow + i) * (long)N + (n0 + wc + ni * 16 + ccol)] =
            (_Float16)v;
      }
}

// ---------------- 8-wave NT GEMM (256x128), wave 64x64 — r15-proven ---------
template <int RELU>
__global__ __launch_bounds__(512, 4) void gemm8_nt(
    const _Float16* __restrict__ A, const _Float16* __restrict__ W,
    const float* __restrict__ bias, _Float16* __restrict__ C, int N, int K,
    int nn, const int* __restrict__ mcount) {
  const int bid = (int)blockIdx.x;
  const int mi = (bid >> 3) / nn;
  const int nt_ = (bid >> 3) - mi * nn;
  const long m0 = (long)(mi * 8 + (bid & 7)) * 256;
  const long n0 = (long)nt_ * 128;
  if (mcount && m0 >= (long)*mcount) return;
  __shared__ __align__(16) _Float16 As[3][256 * 32];   // 48KB
  __shared__ __align__(16) _Float16 Bs[3][128 * 32];   // 24KB
  const int tid = threadIdx.x;
  const int w = tid >> 6;     // 0..7
  const int lane = tid & 63;
  constexpr int LPS = 3;

  const int rA0 = w * 16 + (lane >> 2);
  const int rA1 = rA0 + 128;
  const int cb = lane & 3;
  const int swA0 = (cb ^ ((rA0 >> 1) & 3)) * 8;
  const int swA1 = (cb ^ ((rA1 >> 1) & 3)) * 8;
  const _Float16* gA0 = A + (m0 + rA0) * K + swA0;
  const _Float16* gA1 = A + (m0 + rA1) * K + swA1;
  const _Float16* gB0 = W + (n0 + rA0) * K + swA0;

  const int wr = (w >> 1) * 64;
  const int wc = (w & 1) * 64;
  const int fr = lane & 15;
  const int fkb = lane >> 4;

  f32x4 acc[4][4];
#pragma unroll
  for (int mi2 = 0; mi2 < 4; mi2++)
#pragma unroll
    for (int ni = 0; ni < 4; ni++) acc[mi2][ni] = (f32x4){0.f, 0.f, 0.f, 0.f};

#define STAGE(buf, k0)                                   \
  do {                                                   \
    gld_lds16(gA0 + (k0), &As[buf][w * 512]);            \
    gld_lds16(gA1 + (k0), &As[buf][(w + 8) * 512]);      \
    gld_lds16(gB0 + (k0), &Bs[buf][w * 512]);            \
  } while (0)

#define COMPUTE(buf)                                                          \
  do {                                                                        \
    f16x8 af[4], bf[4];                                                       \
    _Pragma("unroll") for (int i = 0; i < 4; i++) {                           \
      int r_ = wr + i * 16 + fr;                                              \
      af[i] = *(const f16x8*)&As[buf][r_ * 32 + ((fkb ^ ((r_ >> 1) & 3)) * 8)]; \
    }                                                                         \
    _Pragma("unroll") for (int i = 0; i < 4; i++) {                           \
      int r_ = wc + i * 16 + fr;                                              \
      bf[i] = *(const f16x8*)&Bs[buf][r_ * 32 + ((fkb ^ ((r_ >> 1) & 3)) * 8)]; \
    }                                                                         \
    __builtin_amdgcn_s_setprio(1);                                            \
    _Pragma("unroll") for (int mi2 = 0; mi2 < 4; mi2++)                       \
        _Pragma("unroll") for (int ni = 0; ni < 4; ni++)                      \
            acc[mi2][ni] = __builtin_amdgcn_mfma_f32_16x16x32_f16(            \
                af[mi2], bf[ni], acc[mi2][ni], 0, 0, 0);                      \
    __builtin_amdgcn_s_setprio(0);                                            \
  } while (0)

  PIPE_MAIN()
#undef STAGE
#undef COMPUTE

  // epilogue: C/D layout col=lane&15, row=(lane>>4)*4+i  (m89-verified)
  const int crow = (lane >> 4) * 4;
  const int ccol = lane & 15;
  float bv[4];
#pragma unroll
  for (int ni = 0; ni < 4; ni++)
    bv[ni] = bias ? bias[n0 + wc + ni * 16 + ccol] : 0.f;
#pragma unroll
  for (int mi2 = 0; mi2 < 4; mi2++)
#pragma unroll
    for (int ni = 0; ni < 4; ni++)
#pragma unroll
      for (int i = 0; i < 4; i++) {
        float v = acc[mi2][ni][i] + bv[ni];
        if (RELU) v = fmaxf(v, 0.f);
        C[(m0 + wr + mi2 * 16 + crow + i) * (long)N + (n0 + wc + ni * 16 + ccol)] =
            (_Float16)v;
      }
}

// ------- span pooling into precomputed compact slots (no atomics) -----------
__global__ __launch_bounds__(192) void pool_kernel(
    const _Float16* __restrict__ v, const float* __restrict__ scores,
    const int* __restrict__ span_ids, const int* __restrict__ span_masks,
    _Float16* __restrict__ attn, const int* __restrict__ cidx) {
  int r = blockIdx.x;  // b*N + n
  if (span_masks[r] == 0) return;
  int slot = cidx[r];
  int i = threadIdx.x;   // 0..191
  int h = i / 48;        // head
  int d0 = i * 4;
  int b = r >> 12;
  int st = span_ids[2 * r], en = span_ids[2 * r + 1];
  int wdt = en - st;  // 1..8 (block-uniform)
  const float* sc = scores + ((size_t)(b * NHh + h)) * Ss + st;
  float w[8];
  float mx = -1e30f;
#pragma unroll
  for (int j = 0; j < 8; j++) {
    float t = (j < wdt) ? sc[j] : -1e30f;
    w[j] = t;
    mx = fmaxf(mx, t);
  }
  float sum = 0.f;
#pragma unroll
  for (int j = 0; j < 8; j++) {
    float e = (j < wdt) ? expf(w[j] - mx) : 0.f;
    w[j] = e;
    sum += e;
  }
  float inv = 1.f / sum;
  float a0 = 0.f, a1 = 0.f, a2 = 0.f, a3 = 0.f;
#pragma unroll
  for (int j = 0; j < 8; j++) {
    if (j < wdt) {  // block-uniform branch
      f16x4 vv = *(const f16x4*)(v + ((size_t)(b * Ss + st + j)) * Hh + d0);
      float wj = w[j] * inv;
      a0 += wj * (float)vv[0];
      a1 += wj * (float)vv[1];
      a2 += wj * (float)vv[2];
      a3 += wj * (float)vv[3];
    }
  }
  f16x4 o;
  o[0] = (_Float16)a0;
  o[1] = (_Float16)a1;
  o[2] = (_Float16)a2;
  o[3] = (_Float16)a3;
  *(f16x4*)&attn[(size_t)slot * Hh + d0] = o;
}

// ------------- LN0: h1 = LN(X + dq) in-place over compact rows --------------
__global__ __launch_bounds__(256) void ln0_kernel(
    _Float16* __restrict__ X, const float* __restrict__ AddV,
    const float* __restrict__ g, const float* __restrict__ bta,
    const int* __restrict__ mcount) {
  __shared__ float red[4];
  int r = blockIdx.x;
  if (r >= *mcount) return;
  int t = threadIdx.x;
  float xv[3];
#pragma unroll
  for (int e = 0; e < 3; e++) {
    int d = t + 256 * e;
    xv[e] = (float)X[(size_t)r * Hh + d] + AddV[d];
  }
  float s = xv[0] + xv[1] + xv[2];
  s = block_sum256(s, red);
  float mean = s * (1.f / 768.f);
  float vs = 0.f;
#pragma unroll
  for (int e = 0; e < 3; e++) {
    float d = xv[e] - mean;
    vs += d * d;
  }
  vs = block_sum256(vs, red);
  float inv = rsqrtf(vs * (1.f / 768.f) + 1e-5f);
#pragma unroll
  for (int e = 0; e < 3; e++) {
    int d = t + 256 * e;
    X[(size_t)r * Hh + d] = (_Float16)((xv[e] - mean) * inv * g[d] + bta[d]);
  }
}

// ------------- LN1: scatter out[r] = LN(F2[c]+h1[c]) or zeros ---------------
__global__ __launch_bounds__(256) void ln1_kernel(
    const _Float16* __restrict__ F2c, const _Float16* __restrict__ h1c,
    const int* __restrict__ cidx, const float* __restrict__ g,
    const float* __restrict__ bta, const int* __restrict__ mask,
    float* __restrict__ out) {
  __shared__ float red[4];
  int r = blockIdx.x;
  int t = threadIdx.x;
  float* orow = out + (size_t)r * Hh;
  if (mask[r] == 0) {  // block-uniform
#pragma unroll
    for (int e = 0; e < 3; e++) orow[t + 256 * e] = 0.f;
    return;
  }
  int c = cidx[r];
  float xv[3];
#pragma unroll
  for (int e = 0; e < 3; e++) {
    int d = t + 256 * e;
    xv[e] = (float)F2c[(size_t)c * Hh + d] + (float)h1c[(size_t)c * Hh + d];
  }
  float s = xv[0] + xv[1] + xv[2];
  s = block_sum256(s, red);
  float mean = s * (1.f / 768.f);
  float vs = 0.f;
#pragma unroll
  for (int e = 0; e < 3; e++) {
    float d = xv[e] - mean;
    vs += d * d;
  }
  vs = block_sum256(vs, red);
  float inv = rsqrtf(vs * (1.f / 768.f) + 1e-5f);
#pragma unroll
  for (int e = 0; e < 3; e++) {
    int d = t + 256 * e;
    orow[d] = (xv[e] - mean) * inv * g[d] + bta[d];
  }
}

// ===========================================================================
extern "C" void kernel_launch(void* const* d_in, const int* in_sizes, int n_in,
                              void* d_out, int out_size, void* d_ws,
                              size_t ws_size, hipStream_t stream) {
  (void)out_size;
  // --- input sanity guard: mismatch -> zero-ish output signature ------------
  if (n_in != 14) return;
  if (in_sizes[0] != 3145728 || in_sizes[2] != 1769472 ||
      in_sizes[3] != 2304 || in_sizes[4] != 589824 ||
      in_sizes[8] != 2359296 || in_sizes[9] != 3072 ||
      in_sizes[12] != 65536 || in_sizes[13] != 32768)
    return;

  const float* tok   = (const float*)d_in[0];
  const float* dq    = (const float*)d_in[1];
  const float* ipw   = (const float*)d_in[2];   // [2304][768]
  const float* ipb   = (const float*)d_in[3];   // [2304]
  const float* outw  = (const float*)d_in[4];   // [768][768]
  const float* outb  = (const float*)d_in[5];
  const float* lng   = (const float*)d_in[6];
  const float* lnb   = (const float*)d_in[7];
  const float* w1    = (const float*)d_in[8];   // [768][3072]
  const float* b1    = (const float*)d_in[9];
  const float* w2    = (const float*)d_in[10];  // [3072][768]
  const float* b2    = (const float*)d_in[11];
  const int* spid    = (const int*)d_in[12];
  const int* spmask  = (const int*)d_in[13];

  char* ws = (char*)d_ws;
  size_t off = 0;
  auto alloc = [&](size_t bytes) {
    size_t r = off;
    off = (off + bytes + 255) & ~(size_t)255;
    return r;
  };
  _Float16* X16  = (_Float16*)(ws + alloc((size_t)Bb * Ss * Hh * 2));     // 6.3MB
  float* SC      = (float*)(ws + alloc((size_t)Bb * NHh * Ss * 4));       // 64KB
  float* Q       = (float*)(ws + alloc(768 * 4));
  float* Cc      = (float*)(ws + alloc(3072 * 4));
  float* SB      = (float*)(ws + alloc(4 * 4));
  _Float16* WV16 = (_Float16*)(ws + alloc((size_t)768 * 768 * 2));        // 1.2MB
  _Float16* OW16 = (_Float16*)(ws + alloc((size_t)768 * 768 * 2));        // 1.2MB
  _Float16* WT1  = (_Float16*)(ws + alloc((size_t)3072 * 768 * 2));       // 4.7MB
  _Float16* WT2  = (_Float16*)(ws + alloc((size_t)768 * 3072 * 2));       // 4.7MB
  // compact-row buffers, worst-case ROWS active:
  _Float16* ATTN = (_Float16*)(ws + alloc((size_t)ROWS * Hh * 2));        // 50.3MB (later reused as F2)
  _Float16* PROJ = (_Float16*)(ws + alloc((size_t)ROWS * Hh * 2));        // 50.3MB (h1 after LN0)
  _Float16* F1   = (_Float16*)(ws + alloc((size_t)ROWS * 3072 * 2));      // 201.3MB
  if (ws_size < off) return;  // total 320,158,976 B <= bound proven in r8
  _Float16* F2 = ATTN;  // ATTN dead after proj GEMM

  // Compaction metadata aliases the X16 region (X16 dead after V GEMM).
  int* CIDX = (int*)X16;                    // 32768 ints = 128KB
  int* BSUM = (int*)X16 + ROWS;             // 128 ints
  int* BOFF = (int*)X16 + ROWS + SCB;       // 128 ints
  int* CNT  = (int*)X16 + ROWS + 2 * SCB;   // 1 int

  // V16 parks in d_out (dead before ln1 writes d_out).
  _Float16* V16 = (_Float16*)d_out;

  // weight prep
  cvt_kernel<<<576, 256, 0, stream>>>(ipw + (size_t)1536 * 768, WV16);  // Wv
  cvt_kernel<<<576, 256, 0, stream>>>(outw, OW16);
  trcvt_kernel<<<dim3(96, 24), 256, 0, stream>>>(w1, WT1, 768, 3072);
  trcvt_kernel<<<dim3(24, 96), 256, 0, stream>>>(w2, WT2, 3072, 768);

  // x = tok + pe
  x_kernel<<<(Bb * Ss * 384) / 256, 256, 0, stream>>>(tok, X16);
  // q, c, sbias
  q_kernel<<<768, 256, 0, stream>>>(dq, ipw, ipb, Q);
  c_kernel<<<3076, 256, 0, stream>>>(Q, ipw, ipb, Cc, SB);
  // scores
  score_kernel<<<Bb * Ss, 256, 0, stream>>>(X16, Cc, SB, SC);
  // V = x @ Wv^T + bv -> V16 (in d_out)   [4-wave 128x64: 384 blocks]
  gemm_nt<0, 64><<<384, 256, 0, stream>>>(X16, WV16, ipb + 1536, V16,
                                          768, 768, 12, nullptr);
  // deterministic compaction scan (X16 now dead; aliased region)
  scan1_kernel<<<SCB, 256, 0, stream>>>(spmask, BSUM);
  scan2_kernel<<<1, 64, 0, stream>>>(BSUM, BOFF, CNT);
  cidx_kernel<<<SCB, 256, 0, stream>>>(spmask, BOFF, CIDX);
  // span pooling -> compact ATTN via CIDX (vectorized f16x4, 192 thr)
  pool_kernel<<<ROWS, 192, 0, stream>>>(V16, SC, spid, spmask, ATTN, CIDX);
  // proj = ATTN @ out_w^T + out_b -> PROJ  [8-wave 256x128: 128m x 6n]
  gemm8_nt<0><<<768, 512, 0, stream>>>(ATTN, OW16, outb, PROJ,
                                       768, 768, 6, CNT);
  // h1 = LN(proj + dq) in-place (compact rows; gated)
  ln0_kernel<<<ROWS, 256, 0, stream>>>(PROJ, dq, lng, lnb, CNT);
  // ffn1 = relu(h1 @ w1 + b1)  [8-wave 256x128: 128m x 24n]
  gemm8_nt<1><<<3072, 512, 0, stream>>>(PROJ, WT1, b1, F1,
                                        3072, 768, 24, CNT);
  // ffn2 = ffn1 @ w2 + b2 -> F2  [8-wave 256x128: 128m x 6n = 768 blocks]
  gemm8_nt<0><<<768, 512, 0, stream>>>(F1, WT2, b2, F2,
                                       768, 3072, 6, CNT);
  // out[r] = LN(F2[cidx[r]] + h1[cidx[r]]) or zeros -> fp32 d_out
  ln1_kernel<<<ROWS, 256, 0, stream>>>(F2, PROJ, CIDX, lng, lnb, spmask,
                                       (float*)d_out);
}